// Round 3
// baseline (535.525 us; speedup 1.0000x reference)
//
#include <hip/hip_runtime.h>
#include <math.h>

typedef unsigned short u16;
typedef unsigned int   u32;
typedef __attribute__((ext_vector_type(8))) short short8;
typedef __attribute__((ext_vector_type(4))) float f32x4;

// Problem constants
#define B_   256
#define T_   16
#define A_   400
#define N_   8
#define D_   512
#define BT_  4096      // B*T
#define AN_  3200      // A*N
#define BA_  102400    // B*A
#define U_   0.0625f   // 1/T
#define V_   0.125f    // 1/N
#define INV_MEAN (1.0f/1638400.0f)   // 1/(BA*T)
#define NBLK 1600      // sinkhorn blocks (64 thd, 1 problem/lane)

#define RCP(x) __builtin_amdgcn_rcpf(x)

__device__ __forceinline__ u16 f2bf(float x) {
    u32 u = __float_as_uint(x);
    u32 r = (u + 0x7fffu + ((u >> 16) & 1u)) >> 16;
    return (u16)r;
}
__device__ __forceinline__ float bf2f(u16 h) {
    return __uint_as_float(((u32)h) << 16);
}

__device__ __forceinline__ void gl_lds16(const u16* g, void* l) {
    __builtin_amdgcn_global_load_lds(
        (const __attribute__((address_space(1))) void*)g,
        (__attribute__((address_space(3))) void*)l, 16, 0, 0);
}

// ---------------- normalize rows of [nrows][512] + bf16 hi/lo split ----------------
__global__ __launch_bounds__(256)
void norm_k(const float* __restrict__ src, float* __restrict__ dst,
            u16* __restrict__ hi, u16* __restrict__ lo, int nrows)
{
    int wid  = threadIdx.x >> 6;
    int lane = threadIdx.x & 63;
    int row  = blockIdx.x * 4 + wid;
    if (row >= nrows) return;
    const float* s = src + (size_t)row * 512;
    float4 x = *(const float4*)(s + lane * 4);
    float4 y = *(const float4*)(s + 256 + lane * 4);
    float ss = x.x*x.x + x.y*x.y + x.z*x.z + x.w*x.w
             + y.x*y.x + y.y*y.y + y.z*y.z + y.w*y.w;
    ss += __shfl_xor(ss, 1);  ss += __shfl_xor(ss, 2);  ss += __shfl_xor(ss, 4);
    ss += __shfl_xor(ss, 8);  ss += __shfl_xor(ss, 16); ss += __shfl_xor(ss, 32);
    float inv = rsqrtf(ss);
    float v0[4] = {x.x*inv, x.y*inv, x.z*inv, x.w*inv};
    float v1[4] = {y.x*inv, y.y*inv, y.z*inv, y.w*inv};
    float* d = dst + (size_t)row * 512;
    *(float4*)(d + lane * 4)       = make_float4(v0[0], v0[1], v0[2], v0[3]);
    *(float4*)(d + 256 + lane * 4) = make_float4(v1[0], v1[1], v1[2], v1[3]);
    ushort4 h0, h1, l0, l1;
    u16* hp = (u16*)&h0; u16* lp = (u16*)&l0;
    #pragma unroll
    for (int k = 0; k < 4; ++k) { hp[k] = f2bf(v0[k]); lp[k] = f2bf(v0[k] - bf2f(hp[k])); }
    hp = (u16*)&h1; lp = (u16*)&l1;
    #pragma unroll
    for (int k = 0; k < 4; ++k) { hp[k] = f2bf(v1[k]); lp[k] = f2bf(v1[k] - bf2f(hp[k])); }
    *(ushort4*)(hi + (size_t)row * 512 + lane * 4)       = h0;
    *(ushort4*)(hi + (size_t)row * 512 + 256 + lane * 4) = h1;
    *(ushort4*)(lo + (size_t)row * 512 + lane * 4)       = l0;
    *(ushort4*)(lo + (size_t)row * 512 + 256 + lane * 4) = l1;
}

// ---------------- pools ----------------
__global__ __launch_bounds__(256)
void pools_k(const float* __restrict__ imf_n, const float* __restrict__ dsn,
             const float* __restrict__ dtn, float* __restrict__ img_pool,
             float* __restrict__ dsum, int* __restrict__ ifound)
{
    int i = blockIdx.x * 256 + threadIdx.x;
    if (i == 0) { ifound[0] = 0; ifound[1] = 0; }
    if (i < 131072) {               // img_pool: (b,d)
        int b = i >> 9, d = i & 511;
        float s = 0.f;
        #pragma unroll
        for (int t = 0; t < 16; ++t) s += imf_n[((size_t)(b*16 + t))*512 + d];
        img_pool[i] = s * 0.0625f;
    } else if (i < 131072 + 204800) { // dsum: (a,d)
        int k = i - 131072;
        int a = k >> 9, d = k & 511;
        float s1 = 0.f, s2 = 0.f;
        #pragma unroll
        for (int n = 0; n < 8; ++n) {
            s1 += dtn[((size_t)(a*8 + n))*512 + d];
            s2 += dsn[((size_t)(a*8 + n))*512 + d];
        }
        dsum[k] = (s1 + s2) * 0.125f;
    }
}

// ---------------- pooled-logit base ----------------
__global__ __launch_bounds__(256)
void base_k(const float* __restrict__ img_pool, const float* __restrict__ dsum,
            const float* __restrict__ lsc, float* __restrict__ out)
{
    int wid  = threadIdx.x >> 6;
    int lane = threadIdx.x & 63;
    int wg   = blockIdx.x * 4 + wid;
    int b  = wg / 50;
    int ac = wg % 50;
    int ai = lane >> 3, dg = lane & 7;
    int a  = ac * 8 + ai;
    const float* ip = img_pool + (size_t)b * 512 + dg * 64;
    const float* dp = dsum + (size_t)a * 512 + dg * 64;
    float s = 0.f;
    #pragma unroll
    for (int k = 0; k < 64; k += 4) {
        float4 x = *(const float4*)(ip + k);
        float4 y = *(const float4*)(dp + k);
        s = fmaf(x.x, y.x, s); s = fmaf(x.y, y.y, s);
        s = fmaf(x.z, y.z, s); s = fmaf(x.w, y.w, s);
    }
    s += __shfl_xor(s, 1); s += __shfl_xor(s, 2); s += __shfl_xor(s, 4);
    if (dg == 0) {
        float ls = __expf(lsc[0]);
        out[(size_t)b * 400 + a] = 0.5f * ls * s;
    }
}

// ---------------- bf16x3-split MFMA GEMM -> transposed simT[k=t*8+n][p=b*400+a] ----------------
__global__ __launch_bounds__(256)
void gemm_mfma(const u16* __restrict__ Ahi, const u16* __restrict__ Alo,
               const u16* __restrict__ Bhi, const u16* __restrict__ Blo,
               float* __restrict__ C)
{
    __shared__ u16 sm[4][128 * 32];   // Ahi, Alo, Bhi, Blo tiles (8KB each, linear)
    int bid = blockIdx.x;
    int swz = (bid & 7) * 100 + (bid >> 3);     // 800 % 8 == 0: bijective XCD swizzle
    int by = swz / 25, bx = swz % 25;
    int m0 = by * 128, n0 = bx * 128;
    int tid = threadIdx.x, lane = tid & 63, w = tid >> 6;
    int wr = w >> 1, wc = w & 1;
    int srow = tid >> 2, sc = tid & 3;

    f32x4 acc[4][4];
    #pragma unroll
    for (int i = 0; i < 4; ++i)
        #pragma unroll
        for (int jj = 0; jj < 4; ++jj) acc[i][jj] = (f32x4)0.f;

    for (int k0 = 0; k0 < 512; k0 += 32) {
        __syncthreads();
        #pragma unroll
        for (int q = 0; q < 2; ++q) {
            int row = q * 64 + srow;
            int gch = sc ^ ((row >> 2) & 3);   // pre-swizzled global source
            size_t goffA = (size_t)(m0 + row) * 512 + k0 + gch * 8;
            size_t goffB = (size_t)(n0 + row) * 512 + k0 + gch * 8;
            u32 ldso = (u32)(q * 4096 + w * 1024);
            gl_lds16(Ahi + goffA, (char*)sm[0] + ldso);
            gl_lds16(Alo + goffA, (char*)sm[1] + ldso);
            gl_lds16(Bhi + goffB, (char*)sm[2] + ldso);
            gl_lds16(Blo + goffB, (char*)sm[3] + ldso);
        }
        __syncthreads();
        int lr = lane & 15, kg = lane >> 4;
        short8 ah[4], al[4], bh[4], bl[4];
        #pragma unroll
        for (int i = 0; i < 4; ++i) {
            int ar = wr * 64 + i * 16 + lr;
            u32 offa = (u32)(ar * 64 + (kg ^ ((ar >> 2) & 3)) * 16);
            ah[i] = *(const short8*)((const char*)sm[0] + offa);
            al[i] = *(const short8*)((const char*)sm[1] + offa);
            int br = wc * 64 + i * 16 + lr;
            u32 offb = (u32)(br * 64 + (kg ^ ((br >> 2) & 3)) * 16);
            bh[i] = *(const short8*)((const char*)sm[2] + offb);
            bl[i] = *(const short8*)((const char*)sm[3] + offb);
        }
        #pragma unroll
        for (int i = 0; i < 4; ++i)
            #pragma unroll
            for (int jj = 0; jj < 4; ++jj) {
                acc[i][jj] = __builtin_amdgcn_mfma_f32_16x16x32_bf16(ah[i], bh[jj], acc[i][jj], 0, 0, 0);
                acc[i][jj] = __builtin_amdgcn_mfma_f32_16x16x32_bf16(ah[i], bl[jj], acc[i][jj], 0, 0, 0);
                acc[i][jj] = __builtin_amdgcn_mfma_f32_16x16x32_bf16(al[i], bh[jj], acc[i][jj], 0, 0, 0);
            }
    }
    // epilogue: simT[(t*8+n)*BA + b*400 + a]
    int lr = lane & 15, hi4 = (lane >> 4) * 4;
    #pragma unroll
    for (int i = 0; i < 4; ++i) {
        int mb = m0 + wr * 64 + i * 16;          // multiple of 16
        int bi = mb >> 4;
        #pragma unroll
        for (int jj = 0; jj < 4; ++jj) {
            int colg = n0 + wc * 64 + jj * 16 + lr;
            int ai = colg >> 3, nn = colg & 7;
            size_t pbase = (size_t)bi * 400 + ai;
            #pragma unroll
            for (int rr = 0; rr < 4; ++rr) {
                int t = hi4 + rr;
                C[(size_t)(t * 8 + nn) * BA_ + pbase] = acc[i][jj][rr];
            }
        }
    }
}

// ---------------- Sinkhorn stage: 1 problem per lane, K in registers ----------------
// simT: [128][BA]; errs: [100][NBLK]; ckc: [6][8][BA]; ckr: [2][16][BA]
__global__ __launch_bounds__(64, 2)
void sink_stage(const float* __restrict__ simT, float* __restrict__ errs,
                float* __restrict__ ckc, float* __restrict__ ckr,
                const int* __restrict__ fnd, int it0, int it1)
{
    if (it0 > 0 && *fnd) return;
    int p = blockIdx.x * 64 + threadIdx.x;
    float K[16][8];
    #pragma unroll
    for (int t = 0; t < 16; ++t)
        #pragma unroll
        for (int n = 0; n < 8; ++n)
            K[t][n] = __expf((simT[(size_t)(t*8+n)*BA_ + p] - 1.f) * 10.f);
    float c[8], rp[16];
    if (it0 > 0) {
        int slot = it0/16 - 1;
        #pragma unroll
        for (int n = 0; n < 8; ++n) c[n] = ckc[((size_t)(slot*8+n))*BA_ + p];
        int rslot = (it0 == 16) ? 0 : 1;
        #pragma unroll
        for (int t = 0; t < 16; ++t) rp[t] = ckr[((size_t)(rslot*16+t))*BA_ + p];
    } else {
        #pragma unroll
        for (int n = 0; n < 8; ++n) c[n] = 1.f;
        #pragma unroll
        for (int t = 0; t < 16; ++t) rp[t] = 1.f;
    }
    for (int idx = it0; idx < it1; ++idx) {
        float acc[8];
        #pragma unroll
        for (int n = 0; n < 8; ++n) acc[n] = 0.f;
        float e = 0.f;
        #pragma unroll
        for (int t = 0; t < 16; ++t) {
            float s = 0.f;
            #pragma unroll
            for (int n = 0; n < 8; ++n) s = fmaf(K[t][n], c[n], s);
            float r = U_ * RCP(s);
            e += fabsf(r - rp[t]);
            rp[t] = r;
            #pragma unroll
            for (int n = 0; n < 8; ++n) acc[n] = fmaf(K[t][n], r, acc[n]);
        }
        #pragma unroll
        for (int n = 0; n < 8; ++n) c[n] = V_ * RCP(acc[n]);
        e += __shfl_xor(e, 1);  e += __shfl_xor(e, 2);  e += __shfl_xor(e, 4);
        e += __shfl_xor(e, 8);  e += __shfl_xor(e, 16); e += __shfl_xor(e, 32);
        if (threadIdx.x == 0) errs[(size_t)idx * NBLK + blockIdx.x] = e;
        if ((idx & 15) == 15) {
            if (idx < 96) {
                int slot = idx >> 4;
                #pragma unroll
                for (int n = 0; n < 8; ++n) ckc[((size_t)(slot*8+n))*BA_ + p] = c[n];
            }
            if (idx == 15 || idx == 47) {
                int rslot = (idx == 15) ? 0 : 1;
                #pragma unroll
                for (int t = 0; t < 16; ++t) ckr[((size_t)(rslot*16+t))*BA_ + p] = rp[t];
            }
        }
    }
}

// ---------------- fused per-iter reduce + convergence scan (single block) ----------------
__global__ __launch_bounds__(256)
void red_fin_k(const float* __restrict__ errs, int* __restrict__ iters,
               int* __restrict__ fnd, int it0, int it1, int is_final)
{
    if (it0 > 0 && *fnd) return;
    __shared__ float eit[64];
    int nit = it1 - it0;
    int wid = threadIdx.x >> 6, lane = threadIdx.x & 63;
    for (int ii = wid; ii < nit; ii += 4) {
        const float* e = errs + (size_t)(it0 + ii) * NBLK;
        float s = 0.f;
        for (int k = lane; k < NBLK; k += 64) s += e[k];
        s += __shfl_xor(s, 1);  s += __shfl_xor(s, 2);  s += __shfl_xor(s, 4);
        s += __shfl_xor(s, 8);  s += __shfl_xor(s, 16); s += __shfl_xor(s, 32);
        if (lane == 0) eit[ii] = s;
    }
    __syncthreads();
    if (threadIdx.x == 0) {
        for (int ii = 0; ii < nit; ++ii) {
            if (eit[ii] * INV_MEAN < 0.01f) {
                *iters = it0 + ii + 1;
                *fnd = 1;
                return;
            }
        }
        if (is_final) *iters = 100;
    }
}

// ---------------- final pass: resume from checkpoint, score = sum P*sim ----------------
__global__ __launch_bounds__(64, 2)
void sink_final(const float* __restrict__ simT, const float* __restrict__ ckc,
                const int* __restrict__ itr, float* __restrict__ score)
{
    int I = *itr;
    int i0 = ((I - 1) >> 4) << 4;
    int p = blockIdx.x * 64 + threadIdx.x;
    float K[16][8];
    #pragma unroll
    for (int t = 0; t < 16; ++t)
        #pragma unroll
        for (int n = 0; n < 8; ++n)
            K[t][n] = __expf((simT[(size_t)(t*8+n)*BA_ + p] - 1.f) * 10.f);
    float c[8];
    if (i0 > 0) {
        int slot = i0/16 - 1;
        #pragma unroll
        for (int n = 0; n < 8; ++n) c[n] = ckc[((size_t)(slot*8+n))*BA_ + p];
    } else {
        #pragma unroll
        for (int n = 0; n < 8; ++n) c[n] = 1.f;
    }
    float r[16];
    for (int idx = i0; idx < I; ++idx) {
        float acc[8];
        #pragma unroll
        for (int n = 0; n < 8; ++n) acc[n] = 0.f;
        #pragma unroll
        for (int t = 0; t < 16; ++t) {
            float s = 0.f;
            #pragma unroll
            for (int n = 0; n < 8; ++n) s = fmaf(K[t][n], c[n], s);
            r[t] = U_ * RCP(s);
            #pragma unroll
            for (int n = 0; n < 8; ++n) acc[n] = fmaf(K[t][n], r[t], acc[n]);
        }
        #pragma unroll
        for (int n = 0; n < 8; ++n) c[n] = V_ * RCP(acc[n]);
    }
    float g = 0.f;
    #pragma unroll
    for (int t = 0; t < 16; ++t)
        #pragma unroll
        for (int n = 0; n < 8; ++n)
            g = fmaf(r[t] * c[n] * K[t][n], simT[(size_t)(t*8+n)*BA_ + p], g);
    score[p] = g;
}

// ---------------- final combine ----------------
__global__ __launch_bounds__(256)
void finalize_k(const float* __restrict__ st, const float* __restrict__ ss,
                const float* __restrict__ lsc, float* __restrict__ out)
{
    int i = blockIdx.x * 256 + threadIdx.x;
    float ls = __expf(lsc[0]);
    out[i] += 0.5f * ls * (st[i] + ss[i]);
}

extern "C" void kernel_launch(void* const* d_in, const int* in_sizes, int n_in,
                              void* d_out, int out_size, void* d_ws, size_t ws_size,
                              hipStream_t stream)
{
    (void)in_sizes; (void)n_in; (void)out_size; (void)ws_size;
    const float* imf = (const float*)d_in[0];
    const float* ds  = (const float*)d_in[1];   // spatial
    const float* dt  = (const float*)d_in[2];   // temporal
    const float* lsc = (const float*)d_in[3];
    float* out = (float*)d_out;

    float* imf_n    = (float*)d_ws;             // 2,097,152
    float* dsn      = imf_n + 2097152;          // 1,638,400
    float* dtn      = dsn + 1638400;            // 1,638,400
    float* img_pool = dtn + 1638400;            // 131,072
    float* dsum     = img_pool + 131072;        // 204,800
    float* simT     = dsum + 204800;            // 13,107,200
    float* errs     = simT + 13107200;          // 640,000 (use 160,000)
    float* err_iter = errs + 640000;            // 128
    float* ckc      = err_iter + 128;           // 4,915,200
    float* ckr      = ckc + 4915200;            // 3,276,800
    float* score_t  = ckr + 3276800;            // 102,400
    float* score_s  = score_t + 102400;         // 102,400
    int*   ifound   = (int*)(score_s + 102400); // found[2], iters[2]
    u16*   Ahi      = (u16*)(ifound + 4);       // 2,097,152 u16
    u16*   Alo      = Ahi + 2097152;
    u16*   Bshi     = Alo + 2097152;            // 1,638,400 u16 each
    u16*   Bslo     = Bshi + 1638400;
    u16*   Bthi     = Bslo + 1638400;
    u16*   Btlo     = Bthi + 1638400;
    (void)err_iter;

    norm_k<<<1024, 256, 0, stream>>>(imf, imf_n, Ahi, Alo, 4096);
    norm_k<<<800, 256, 0, stream>>>(ds, dsn, Bshi, Bslo, 3200);
    norm_k<<<800, 256, 0, stream>>>(dt, dtn, Bthi, Btlo, 3200);
    pools_k<<<1312, 256, 0, stream>>>(imf_n, dsn, dtn, img_pool, dsum, ifound);
    base_k<<<3200, 256, 0, stream>>>(img_pool, dsum, lsc, out);

    for (int set = 0; set < 2; ++set) {
        const u16* Bh = (set == 0) ? Bthi : Bshi;   // temporal first
        const u16* Bl = (set == 0) ? Btlo : Bslo;
        float* score = (set == 0) ? score_t : score_s;
        int* fnd = ifound + set;
        int* itr = ifound + 2 + set;
        gemm_mfma<<<800, 256, 0, stream>>>(Ahi, Alo, Bh, Bl, simT);
        sink_stage<<<NBLK, 64, 0, stream>>>(simT, errs, ckc, ckr, fnd, 0, 16);
        red_fin_k<<<1, 256, 0, stream>>>(errs, itr, fnd, 0, 16, 0);
        sink_stage<<<NBLK, 64, 0, stream>>>(simT, errs, ckc, ckr, fnd, 16, 48);
        red_fin_k<<<1, 256, 0, stream>>>(errs, itr, fnd, 16, 48, 0);
        sink_stage<<<NBLK, 64, 0, stream>>>(simT, errs, ckc, ckr, fnd, 48, 100);
        red_fin_k<<<1, 256, 0, stream>>>(errs, itr, fnd, 48, 100, 1);
        sink_final<<<NBLK, 64, 0, stream>>>(simT, ckc, itr, score);
    }

    finalize_k<<<400, 256, 0, stream>>>(score_t, score_s, lsc, out);
}

// Round 4
// 488.498 us; speedup vs baseline: 1.0963x; 1.0963x over previous
//
#include <hip/hip_runtime.h>
#include <math.h>

typedef unsigned short u16;
typedef unsigned int   u32;
typedef __attribute__((ext_vector_type(8))) short short8;
typedef __attribute__((ext_vector_type(4))) float f32x4;
typedef __attribute__((ext_vector_type(2))) float f32x2;

// Problem constants
#define B_   256
#define T_   16
#define A_   400
#define N_   8
#define D_   512
#define BT_  4096      // B*T
#define AN_  3200      // A*N
#define BA_  102400    // B*A
#define U_   0.0625f   // 1/T
#define V_   0.125f    // 1/N
#define INV_MEAN (1.0f/1638400.0f)   // 1/(BA*T)
#define NBLK 1600      // sinkhorn blocks (64 thd, 1 problem/lane)

#define RCP(x) __builtin_amdgcn_rcpf(x)
#define PKFMA(a, b, c) __builtin_elementwise_fma((a), (b), (c))

__device__ __forceinline__ u16 f2bf(float x) {
    u32 u = __float_as_uint(x);
    u32 r = (u + 0x7fffu + ((u >> 16) & 1u)) >> 16;
    return (u16)r;
}
__device__ __forceinline__ float bf2f(u16 h) {
    return __uint_as_float(((u32)h) << 16);
}

__device__ __forceinline__ void gl_lds16(const u16* g, void* l) {
    __builtin_amdgcn_global_load_lds(
        (const __attribute__((address_space(1))) void*)g,
        (__attribute__((address_space(3))) void*)l, 16, 0, 0);
}

// ---------------- normalize rows of [nrows][512] + bf16 hi/lo split ----------------
__global__ __launch_bounds__(256)
void norm_k(const float* __restrict__ src, float* __restrict__ dst,
            u16* __restrict__ hi, u16* __restrict__ lo, int nrows)
{
    int wid  = threadIdx.x >> 6;
    int lane = threadIdx.x & 63;
    int row  = blockIdx.x * 4 + wid;
    if (row >= nrows) return;
    const float* s = src + (size_t)row * 512;
    float4 x = *(const float4*)(s + lane * 4);
    float4 y = *(const float4*)(s + 256 + lane * 4);
    float ss = x.x*x.x + x.y*x.y + x.z*x.z + x.w*x.w
             + y.x*y.x + y.y*y.y + y.z*y.z + y.w*y.w;
    ss += __shfl_xor(ss, 1);  ss += __shfl_xor(ss, 2);  ss += __shfl_xor(ss, 4);
    ss += __shfl_xor(ss, 8);  ss += __shfl_xor(ss, 16); ss += __shfl_xor(ss, 32);
    float inv = rsqrtf(ss);
    float v0[4] = {x.x*inv, x.y*inv, x.z*inv, x.w*inv};
    float v1[4] = {y.x*inv, y.y*inv, y.z*inv, y.w*inv};
    float* d = dst + (size_t)row * 512;
    *(float4*)(d + lane * 4)       = make_float4(v0[0], v0[1], v0[2], v0[3]);
    *(float4*)(d + 256 + lane * 4) = make_float4(v1[0], v1[1], v1[2], v1[3]);
    ushort4 h0, h1, l0, l1;
    u16* hp = (u16*)&h0; u16* lp = (u16*)&l0;
    #pragma unroll
    for (int k = 0; k < 4; ++k) { hp[k] = f2bf(v0[k]); lp[k] = f2bf(v0[k] - bf2f(hp[k])); }
    hp = (u16*)&h1; lp = (u16*)&l1;
    #pragma unroll
    for (int k = 0; k < 4; ++k) { hp[k] = f2bf(v1[k]); lp[k] = f2bf(v1[k] - bf2f(hp[k])); }
    *(ushort4*)(hi + (size_t)row * 512 + lane * 4)       = h0;
    *(ushort4*)(hi + (size_t)row * 512 + 256 + lane * 4) = h1;
    *(ushort4*)(lo + (size_t)row * 512 + lane * 4)       = l0;
    *(ushort4*)(lo + (size_t)row * 512 + 256 + lane * 4) = l1;
}

// ---------------- pools ----------------
__global__ __launch_bounds__(256)
void pools_k(const float* __restrict__ imf_n, const float* __restrict__ dsn,
             const float* __restrict__ dtn, float* __restrict__ img_pool,
             float* __restrict__ dsum, int* __restrict__ ifound)
{
    int i = blockIdx.x * 256 + threadIdx.x;
    if (i == 0) { ifound[0] = 0; ifound[1] = 0; }
    if (i < 131072) {               // img_pool: (b,d)
        int b = i >> 9, d = i & 511;
        float s = 0.f;
        #pragma unroll
        for (int t = 0; t < 16; ++t) s += imf_n[((size_t)(b*16 + t))*512 + d];
        img_pool[i] = s * 0.0625f;
    } else if (i < 131072 + 204800) { // dsum: (a,d)
        int k = i - 131072;
        int a = k >> 9, d = k & 511;
        float s1 = 0.f, s2 = 0.f;
        #pragma unroll
        for (int n = 0; n < 8; ++n) {
            s1 += dtn[((size_t)(a*8 + n))*512 + d];
            s2 += dsn[((size_t)(a*8 + n))*512 + d];
        }
        dsum[k] = (s1 + s2) * 0.125f;
    }
}

// ---------------- pooled-logit base ----------------
__global__ __launch_bounds__(256)
void base_k(const float* __restrict__ img_pool, const float* __restrict__ dsum,
            const float* __restrict__ lsc, float* __restrict__ out)
{
    int wid  = threadIdx.x >> 6;
    int lane = threadIdx.x & 63;
    int wg   = blockIdx.x * 4 + wid;
    int b  = wg / 50;
    int ac = wg % 50;
    int ai = lane >> 3, dg = lane & 7;
    int a  = ac * 8 + ai;
    const float* ip = img_pool + (size_t)b * 512 + dg * 64;
    const float* dp = dsum + (size_t)a * 512 + dg * 64;
    float s = 0.f;
    #pragma unroll
    for (int k = 0; k < 64; k += 4) {
        float4 x = *(const float4*)(ip + k);
        float4 y = *(const float4*)(dp + k);
        s = fmaf(x.x, y.x, s); s = fmaf(x.y, y.y, s);
        s = fmaf(x.z, y.z, s); s = fmaf(x.w, y.w, s);
    }
    s += __shfl_xor(s, 1); s += __shfl_xor(s, 2); s += __shfl_xor(s, 4);
    if (dg == 0) {
        float ls = __expf(lsc[0]);
        out[(size_t)b * 400 + a] = 0.5f * ls * s;
    }
}

// ---------------- bf16x3-split MFMA GEMM -> simT[k=t*8+n][p'] ----------------
// p' = ((by*25+bx)*8 + (b&7))*16 + (a&15)   (tile-local contiguous ordering)
__global__ __launch_bounds__(256)
void gemm_mfma(const u16* __restrict__ Ahi, const u16* __restrict__ Alo,
               const u16* __restrict__ Bhi, const u16* __restrict__ Blo,
               float* __restrict__ C)
{
    __shared__ alignas(16) char smraw[32768];
    u16* s0 = (u16*)smraw;          // Ahi tile 8KB
    u16* s1 = s0 + 4096;            // Alo
    u16* s2 = s0 + 8192;            // Bhi
    u16* s3 = s0 + 12288;           // Blo
    int bid = blockIdx.x;
    int swz = (bid & 7) * 100 + (bid >> 3);     // 800 % 8 == 0: bijective XCD swizzle
    int by = swz / 25, bx = swz % 25;
    int m0 = by * 128, n0 = bx * 128;
    int pblk = (by * 25 + bx) * 128;
    int tid = threadIdx.x, lane = tid & 63, w = tid >> 6;
    int wr = w >> 1, wc = w & 1;
    int srow = tid >> 2, sc = tid & 3;

    f32x4 acc[4][4];
    #pragma unroll
    for (int i = 0; i < 4; ++i)
        #pragma unroll
        for (int jj = 0; jj < 4; ++jj) acc[i][jj] = (f32x4)0.f;

    for (int k0 = 0; k0 < 512; k0 += 32) {
        __syncthreads();
        #pragma unroll
        for (int q = 0; q < 2; ++q) {
            int row = q * 64 + srow;
            int gch = sc ^ ((row >> 2) & 3);   // pre-swizzled global source
            size_t goffA = (size_t)(m0 + row) * 512 + k0 + gch * 8;
            size_t goffB = (size_t)(n0 + row) * 512 + k0 + gch * 8;
            u32 ldso = (u32)(q * 4096 + w * 1024);
            gl_lds16(Ahi + goffA, (char*)s0 + ldso);
            gl_lds16(Alo + goffA, (char*)s1 + ldso);
            gl_lds16(Bhi + goffB, (char*)s2 + ldso);
            gl_lds16(Blo + goffB, (char*)s3 + ldso);
        }
        __syncthreads();
        int lr16 = lane & 15, kg = lane >> 4;
        short8 ah[4], al[4], bh[4], bl[4];
        #pragma unroll
        for (int i = 0; i < 4; ++i) {
            int ar = wr * 64 + i * 16 + lr16;
            u32 offa = (u32)(ar * 64 + (kg ^ ((ar >> 2) & 3)) * 16);
            ah[i] = *(const short8*)((const char*)s0 + offa);
            al[i] = *(const short8*)((const char*)s1 + offa);
            int br = wc * 64 + i * 16 + lr16;
            u32 offb = (u32)(br * 64 + (kg ^ ((br >> 2) & 3)) * 16);
            bh[i] = *(const short8*)((const char*)s2 + offb);
            bl[i] = *(const short8*)((const char*)s3 + offb);
        }
        #pragma unroll
        for (int i = 0; i < 4; ++i)
            #pragma unroll
            for (int jj = 0; jj < 4; ++jj) {
                acc[i][jj] = __builtin_amdgcn_mfma_f32_16x16x32_bf16(ah[i], bh[jj], acc[i][jj], 0, 0, 0);
                acc[i][jj] = __builtin_amdgcn_mfma_f32_16x16x32_bf16(ah[i], bl[jj], acc[i][jj], 0, 0, 0);
                acc[i][jj] = __builtin_amdgcn_mfma_f32_16x16x32_bf16(al[i], bh[jj], acc[i][jj], 0, 0, 0);
            }
    }

    // ---- LDS-transpose epilogue: two passes of [64 k][128 p], XOR-swizzled ----
    // thread value (i,jj,rr): k = (hi4+rr)*8 + (lr&7), p = (wr*4+i)*16 + wc*8 + jj*2 + (lr>>3)
    float* TB = (float*)smraw;      // 8192 floats = 32KB
    int lr = lane & 15;
    int hi4 = (lane >> 4) * 4;
    int myhalf = lane >> 5;         // t = hi4+rr: lanes<32 -> t<8 (k<64), lanes>=32 -> k>=64
    int pq = (tid & 31) * 4;
    int kw = tid >> 5;              // 0..7
    __syncthreads();
    #pragma unroll
    for (int h = 0; h < 2; ++h) {
        if (myhalf == h) {
            #pragma unroll
            for (int i = 0; i < 4; ++i)
                #pragma unroll
                for (int jj = 0; jj < 4; ++jj) {
                    int pbase = (wr * 4 + i) * 16 + wc * 8 + jj * 2 + (lr >> 3);
                    int psw = pbase ^ ((lr & 7) << 2);
                    #pragma unroll
                    for (int rr = 0; rr < 4; ++rr) {
                        int kk = ((hi4 & 7) + rr) * 8 + (lr & 7);   // k_local in [0,64)
                        TB[kk * 128 + psw] = acc[i][jj][rr];
                    }
                }
        }
        __syncthreads();
        #pragma unroll
        for (int rep = 0; rep < 8; ++rep) {
            int kl = rep * 8 + kw;
            float4 v = *(const float4*)&TB[kl * 128 + (pq ^ (kw << 2))];
            *(float4*)&C[(size_t)(h * 64 + kl) * BA_ + pblk + pq] = v;
        }
        if (h == 0) __syncthreads();
    }
}

// ---------------- Sinkhorn stage: 1 problem per lane, K in registers (f32x2 packed) ----------------
// simT: [128][BA]; errs: [100][NBLK]; ckc: [6][8][BA]; ckr: [2][16][BA]
__global__ __launch_bounds__(64, 2)
void sink_stage(const float* __restrict__ simT, float* __restrict__ errs,
                float* __restrict__ ckc, float* __restrict__ ckr,
                const int* __restrict__ fnd, int it0, int it1)
{
    if (it0 > 0 && *fnd) return;
    int p = blockIdx.x * 64 + threadIdx.x;
    f32x2 Kv[16][4];
    #pragma unroll
    for (int t = 0; t < 16; ++t)
        #pragma unroll
        for (int n2 = 0; n2 < 4; ++n2) {
            float a0 = simT[(size_t)(t*8 + 2*n2    )*BA_ + p];
            float a1 = simT[(size_t)(t*8 + 2*n2 + 1)*BA_ + p];
            f32x2 kv; kv.x = __expf((a0 - 1.f)*10.f); kv.y = __expf((a1 - 1.f)*10.f);
            Kv[t][n2] = kv;
        }
    f32x2 c2[4];
    float rp[16];
    if (it0 > 0) {
        int slot = it0/16 - 1;
        #pragma unroll
        for (int n2 = 0; n2 < 4; ++n2) {
            f32x2 cv;
            cv.x = ckc[((size_t)(slot*8 + 2*n2    ))*BA_ + p];
            cv.y = ckc[((size_t)(slot*8 + 2*n2 + 1))*BA_ + p];
            c2[n2] = cv;
        }
        int rslot = (it0 == 16) ? 0 : 1;
        #pragma unroll
        for (int t = 0; t < 16; ++t) rp[t] = ckr[((size_t)(rslot*16+t))*BA_ + p];
    } else {
        #pragma unroll
        for (int n2 = 0; n2 < 4; ++n2) c2[n2] = (f32x2)1.f;
        #pragma unroll
        for (int t = 0; t < 16; ++t) rp[t] = 1.f;
    }
    for (int idx = it0; idx < it1; ++idx) {
        f32x2 acc2[4];
        #pragma unroll
        for (int n2 = 0; n2 < 4; ++n2) acc2[n2] = (f32x2)0.f;
        float e = 0.f;
        #pragma unroll
        for (int t = 0; t < 16; ++t) {
            f32x2 s2 = Kv[t][0] * c2[0];
            s2 = PKFMA(Kv[t][1], c2[1], s2);
            s2 = PKFMA(Kv[t][2], c2[2], s2);
            s2 = PKFMA(Kv[t][3], c2[3], s2);
            float r = U_ * RCP(s2.x + s2.y);
            e += fabsf(r - rp[t]);
            rp[t] = r;
            f32x2 rv; rv.x = r; rv.y = r;
            #pragma unroll
            for (int n2 = 0; n2 < 4; ++n2) acc2[n2] = PKFMA(Kv[t][n2], rv, acc2[n2]);
        }
        #pragma unroll
        for (int n2 = 0; n2 < 4; ++n2) {
            f32x2 cv; cv.x = V_ * RCP(acc2[n2].x); cv.y = V_ * RCP(acc2[n2].y);
            c2[n2] = cv;
        }
        e += __shfl_xor(e, 1);  e += __shfl_xor(e, 2);  e += __shfl_xor(e, 4);
        e += __shfl_xor(e, 8);  e += __shfl_xor(e, 16); e += __shfl_xor(e, 32);
        if (threadIdx.x == 0) errs[(size_t)idx * NBLK + blockIdx.x] = e;
        if ((idx & 15) == 15) {
            if (idx < 96) {
                int slot = idx >> 4;
                #pragma unroll
                for (int n2 = 0; n2 < 4; ++n2) {
                    ckc[((size_t)(slot*8 + 2*n2    ))*BA_ + p] = c2[n2].x;
                    ckc[((size_t)(slot*8 + 2*n2 + 1))*BA_ + p] = c2[n2].y;
                }
            }
            if (idx == 15 || idx == 47) {
                int rslot = (idx == 15) ? 0 : 1;
                #pragma unroll
                for (int t = 0; t < 16; ++t) ckr[((size_t)(rslot*16+t))*BA_ + p] = rp[t];
            }
        }
    }
}

// ---------------- fused per-iter reduce + convergence scan (single block) ----------------
__global__ __launch_bounds__(256)
void red_fin_k(const float* __restrict__ errs, int* __restrict__ iters,
               int* __restrict__ fnd, int it0, int it1, int is_final)
{
    if (it0 > 0 && *fnd) return;
    __shared__ float eit[64];
    int nit = it1 - it0;
    int wid = threadIdx.x >> 6, lane = threadIdx.x & 63;
    for (int ii = wid; ii < nit; ii += 4) {
        const float* e = errs + (size_t)(it0 + ii) * NBLK;
        float s = 0.f;
        for (int k = lane; k < NBLK; k += 64) s += e[k];
        s += __shfl_xor(s, 1);  s += __shfl_xor(s, 2);  s += __shfl_xor(s, 4);
        s += __shfl_xor(s, 8);  s += __shfl_xor(s, 16); s += __shfl_xor(s, 32);
        if (lane == 0) eit[ii] = s;
    }
    __syncthreads();
    if (threadIdx.x == 0) {
        for (int ii = 0; ii < nit; ++ii) {
            if (eit[ii] * INV_MEAN < 0.01f) {
                *iters = it0 + ii + 1;
                *fnd = 1;
                return;
            }
        }
        if (is_final) *iters = 100;
    }
}

// ---------------- final pass: resume from checkpoint, score = sum P*sim ----------------
__global__ __launch_bounds__(64, 2)
void sink_final(const float* __restrict__ simT, const float* __restrict__ ckc,
                const int* __restrict__ itr, float* __restrict__ score)
{
    int I = *itr;
    int i0 = ((I - 1) >> 4) << 4;
    int p = blockIdx.x * 64 + threadIdx.x;
    f32x2 Kv[16][4];
    #pragma unroll
    for (int t = 0; t < 16; ++t)
        #pragma unroll
        for (int n2 = 0; n2 < 4; ++n2) {
            float a0 = simT[(size_t)(t*8 + 2*n2    )*BA_ + p];
            float a1 = simT[(size_t)(t*8 + 2*n2 + 1)*BA_ + p];
            f32x2 kv; kv.x = __expf((a0 - 1.f)*10.f); kv.y = __expf((a1 - 1.f)*10.f);
            Kv[t][n2] = kv;
        }
    f32x2 c2[4];
    if (i0 > 0) {
        int slot = i0/16 - 1;
        #pragma unroll
        for (int n2 = 0; n2 < 4; ++n2) {
            f32x2 cv;
            cv.x = ckc[((size_t)(slot*8 + 2*n2    ))*BA_ + p];
            cv.y = ckc[((size_t)(slot*8 + 2*n2 + 1))*BA_ + p];
            c2[n2] = cv;
        }
    } else {
        #pragma unroll
        for (int n2 = 0; n2 < 4; ++n2) c2[n2] = (f32x2)1.f;
    }
    float r[16];
    for (int idx = i0; idx < I; ++idx) {
        f32x2 acc2[4];
        #pragma unroll
        for (int n2 = 0; n2 < 4; ++n2) acc2[n2] = (f32x2)0.f;
        #pragma unroll
        for (int t = 0; t < 16; ++t) {
            f32x2 s2 = Kv[t][0] * c2[0];
            s2 = PKFMA(Kv[t][1], c2[1], s2);
            s2 = PKFMA(Kv[t][2], c2[2], s2);
            s2 = PKFMA(Kv[t][3], c2[3], s2);
            r[t] = U_ * RCP(s2.x + s2.y);
            f32x2 rv; rv.x = r[t]; rv.y = r[t];
            #pragma unroll
            for (int n2 = 0; n2 < 4; ++n2) acc2[n2] = PKFMA(Kv[t][n2], rv, acc2[n2]);
        }
        #pragma unroll
        for (int n2 = 0; n2 < 4; ++n2) {
            f32x2 cv; cv.x = V_ * RCP(acc2[n2].x); cv.y = V_ * RCP(acc2[n2].y);
            c2[n2] = cv;
        }
    }
    f32x2 g2 = (f32x2)0.f;
    #pragma unroll
    for (int t = 0; t < 16; ++t) {
        f32x2 rv; rv.x = r[t]; rv.y = r[t];
        #pragma unroll
        for (int n2 = 0; n2 < 4; ++n2) {
            f32x2 sv;
            sv.x = simT[(size_t)(t*8 + 2*n2    )*BA_ + p];
            sv.y = simT[(size_t)(t*8 + 2*n2 + 1)*BA_ + p];
            g2 = PKFMA(Kv[t][n2] * c2[n2] * rv, sv, g2);
        }
    }
    score[p] = g2.x + g2.y;
}

// ---------------- final combine (inverts the tile-local p' permutation) ----------------
__global__ __launch_bounds__(256)
void finalize_k(const float* __restrict__ st, const float* __restrict__ ss,
                const float* __restrict__ lsc, float* __restrict__ out)
{
    int i = blockIdx.x * 256 + threadIdx.x;
    int b = i / 400, a = i - b * 400;
    int pp = (((b >> 3) * 25 + (a >> 4)) * 8 + (b & 7)) * 16 + (a & 15);
    float ls = __expf(lsc[0]);
    out[i] += 0.5f * ls * (st[pp] + ss[pp]);
}

extern "C" void kernel_launch(void* const* d_in, const int* in_sizes, int n_in,
                              void* d_out, int out_size, void* d_ws, size_t ws_size,
                              hipStream_t stream)
{
    (void)in_sizes; (void)n_in; (void)out_size; (void)ws_size;
    const float* imf = (const float*)d_in[0];
    const float* ds  = (const float*)d_in[1];   // spatial
    const float* dt  = (const float*)d_in[2];   // temporal
    const float* lsc = (const float*)d_in[3];
    float* out = (float*)d_out;

    float* imf_n    = (float*)d_ws;             // 2,097,152
    float* dsn      = imf_n + 2097152;          // 1,638,400
    float* dtn      = dsn + 1638400;            // 1,638,400
    float* img_pool = dtn + 1638400;            // 131,072
    float* dsum     = img_pool + 131072;        // 204,800
    float* simT     = dsum + 204800;            // 13,107,200
    float* errs     = simT + 13107200;          // 640,000 (use 160,000)
    float* err_iter = errs + 640000;            // 128
    float* ckc      = err_iter + 128;           // 4,915,200
    float* ckr      = ckc + 4915200;            // 3,276,800
    float* score_t  = ckr + 3276800;            // 102,400
    float* score_s  = score_t + 102400;         // 102,400
    int*   ifound   = (int*)(score_s + 102400); // found[2], iters[2]
    u16*   Ahi      = (u16*)(ifound + 4);       // 2,097,152 u16
    u16*   Alo      = Ahi + 2097152;
    u16*   Bshi     = Alo + 2097152;            // 1,638,400 u16 each
    u16*   Bslo     = Bshi + 1638400;
    u16*   Bthi     = Bslo + 1638400;
    u16*   Btlo     = Bthi + 1638400;
    (void)err_iter;

    norm_k<<<1024, 256, 0, stream>>>(imf, imf_n, Ahi, Alo, 4096);
    norm_k<<<800, 256, 0, stream>>>(ds, dsn, Bshi, Bslo, 3200);
    norm_k<<<800, 256, 0, stream>>>(dt, dtn, Bthi, Btlo, 3200);
    pools_k<<<1312, 256, 0, stream>>>(imf_n, dsn, dtn, img_pool, dsum, ifound);
    base_k<<<3200, 256, 0, stream>>>(img_pool, dsum, lsc, out);

    for (int set = 0; set < 2; ++set) {
        const u16* Bh = (set == 0) ? Bthi : Bshi;   // temporal first
        const u16* Bl = (set == 0) ? Btlo : Bslo;
        float* score = (set == 0) ? score_t : score_s;
        int* fnd = ifound + set;
        int* itr = ifound + 2 + set;
        gemm_mfma<<<800, 256, 0, stream>>>(Ahi, Alo, Bh, Bl, simT);
        sink_stage<<<NBLK, 64, 0, stream>>>(simT, errs, ckc, ckr, fnd, 0, 16);
        red_fin_k<<<1, 256, 0, stream>>>(errs, itr, fnd, 0, 16, 0);
        sink_stage<<<NBLK, 64, 0, stream>>>(simT, errs, ckc, ckr, fnd, 16, 48);
        red_fin_k<<<1, 256, 0, stream>>>(errs, itr, fnd, 16, 48, 0);
        sink_stage<<<NBLK, 64, 0, stream>>>(simT, errs, ckc, ckr, fnd, 48, 100);
        red_fin_k<<<1, 256, 0, stream>>>(errs, itr, fnd, 48, 100, 1);
        sink_final<<<NBLK, 64, 0, stream>>>(simT, ckc, itr, score);
    }

    finalize_k<<<400, 256, 0, stream>>>(score_t, score_s, lsc, out);
}

// Round 7
// 418.144 us; speedup vs baseline: 1.2807x; 1.1683x over previous
//
#include <hip/hip_runtime.h>
#include <math.h>

typedef unsigned short u16;
typedef unsigned int   u32;
typedef __attribute__((ext_vector_type(8))) short short8;
typedef __attribute__((ext_vector_type(4))) float f32x4;
typedef __attribute__((ext_vector_type(2))) float f32x2;

// Problem constants
#define B_   256
#define T_   16
#define A_   400
#define N_   8
#define D_   512
#define BT_  4096      // B*T
#define AN_  3200      // A*N
#define BA_  102400    // B*A
#define U_   0.0625f   // 1/T
#define V_   0.125f    // 1/N
#define INV_MEAN (1.0f/1638400.0f)   // 1/(BA*T)
#define NBLK 1600      // sinkhorn blocks (64 thd, 1 problem/lane)

#define RCP(x) __builtin_amdgcn_rcpf(x)
#define PKFMA(a, b, c) __builtin_elementwise_fma((a), (b), (c))

__device__ __forceinline__ u16 f2bf(float x) {
    u32 u = __float_as_uint(x);
    u32 r = (u + 0x7fffu + ((u >> 16) & 1u)) >> 16;
    return (u16)r;
}
__device__ __forceinline__ float bf2f(u16 h) {
    return __uint_as_float(((u32)h) << 16);
}

__device__ __forceinline__ void gl_lds16(const u16* g, void* l) {
    __builtin_amdgcn_global_load_lds(
        (const __attribute__((address_space(1))) void*)g,
        (__attribute__((address_space(3))) void*)l, 16, 0, 0);
}

// ---------------- normalize rows (all 3 tensors, one launch) + bf16 hi/lo split ----------------
__global__ __launch_bounds__(256)
void norm3_k(const float* __restrict__ imf, const float* __restrict__ ds,
             const float* __restrict__ dt, float* __restrict__ imf_n,
             float* __restrict__ dsn, float* __restrict__ dtn,
             u16* __restrict__ Ahi, u16* __restrict__ Alo,
             u16* __restrict__ Bshi, u16* __restrict__ Bslo,
             u16* __restrict__ Bthi, u16* __restrict__ Btlo)
{
    int blk = blockIdx.x;
    const float* src; float* dst; u16* hi; u16* lo; int rbase;
    if (blk < 1024)      { src = imf; dst = imf_n; hi = Ahi;  lo = Alo;  rbase = blk * 4; }
    else if (blk < 1824) { src = ds;  dst = dsn;   hi = Bshi; lo = Bslo; rbase = (blk - 1024) * 4; }
    else                 { src = dt;  dst = dtn;   hi = Bthi; lo = Btlo; rbase = (blk - 1824) * 4; }
    int wid  = threadIdx.x >> 6;
    int lane = threadIdx.x & 63;
    int row  = rbase + wid;
    const float* s = src + (size_t)row * 512;
    float4 x = *(const float4*)(s + lane * 4);
    float4 y = *(const float4*)(s + 256 + lane * 4);
    float ss = x.x*x.x + x.y*x.y + x.z*x.z + x.w*x.w
             + y.x*y.x + y.y*y.y + y.z*y.z + y.w*y.w;
    ss += __shfl_xor(ss, 1);  ss += __shfl_xor(ss, 2);  ss += __shfl_xor(ss, 4);
    ss += __shfl_xor(ss, 8);  ss += __shfl_xor(ss, 16); ss += __shfl_xor(ss, 32);
    float inv = rsqrtf(ss);
    float v0[4] = {x.x*inv, x.y*inv, x.z*inv, x.w*inv};
    float v1[4] = {y.x*inv, y.y*inv, y.z*inv, y.w*inv};
    float* d = dst + (size_t)row * 512;
    *(float4*)(d + lane * 4)       = make_float4(v0[0], v0[1], v0[2], v0[3]);
    *(float4*)(d + 256 + lane * 4) = make_float4(v1[0], v1[1], v1[2], v1[3]);
    ushort4 h0, h1, l0, l1;
    u16* hp = (u16*)&h0; u16* lp = (u16*)&l0;
    #pragma unroll
    for (int k = 0; k < 4; ++k) { hp[k] = f2bf(v0[k]); lp[k] = f2bf(v0[k] - bf2f(hp[k])); }
    hp = (u16*)&h1; lp = (u16*)&l1;
    #pragma unroll
    for (int k = 0; k < 4; ++k) { hp[k] = f2bf(v1[k]); lp[k] = f2bf(v1[k] - bf2f(hp[k])); }
    *(ushort4*)(hi + (size_t)row * 512 + lane * 4)       = h0;
    *(ushort4*)(hi + (size_t)row * 512 + 256 + lane * 4) = h1;
    *(ushort4*)(lo + (size_t)row * 512 + lane * 4)       = l0;
    *(ushort4*)(lo + (size_t)row * 512 + 256 + lane * 4) = l1;
}

// ---------------- pools ----------------
__global__ __launch_bounds__(256)
void pools_k(const float* __restrict__ imf_n, const float* __restrict__ dsn,
             const float* __restrict__ dtn, float* __restrict__ img_pool,
             float* __restrict__ dsum, int* __restrict__ ifound)
{
    int i = blockIdx.x * 256 + threadIdx.x;
    if (i == 0) { ifound[0] = 0; ifound[1] = 0; }
    if (i < 131072) {               // img_pool: (b,d)
        int b = i >> 9, d = i & 511;
        float s = 0.f;
        #pragma unroll
        for (int t = 0; t < 16; ++t) s += imf_n[((size_t)(b*16 + t))*512 + d];
        img_pool[i] = s * 0.0625f;
    } else if (i < 131072 + 204800) { // dsum: (a,d)
        int k = i - 131072;
        int a = k >> 9, d = k & 511;
        float s1 = 0.f, s2 = 0.f;
        #pragma unroll
        for (int n = 0; n < 8; ++n) {
            s1 += dtn[((size_t)(a*8 + n))*512 + d];
            s2 += dsn[((size_t)(a*8 + n))*512 + d];
        }
        dsum[k] = (s1 + s2) * 0.125f;
    }
}

// ---------------- pooled-logit base ----------------
__global__ __launch_bounds__(256)
void base_k(const float* __restrict__ img_pool, const float* __restrict__ dsum,
            const float* __restrict__ lsc, float* __restrict__ out)
{
    int wid  = threadIdx.x >> 6;
    int lane = threadIdx.x & 63;
    int wg   = blockIdx.x * 4 + wid;
    int b  = wg / 50;
    int ac = wg % 50;
    int ai = lane >> 3, dg = lane & 7;
    int a  = ac * 8 + ai;
    const float* ip = img_pool + (size_t)b * 512 + dg * 64;
    const float* dp = dsum + (size_t)a * 512 + dg * 64;
    float s = 0.f;
    #pragma unroll
    for (int k = 0; k < 64; k += 4) {
        float4 x = *(const float4*)(ip + k);
        float4 y = *(const float4*)(dp + k);
        s = fmaf(x.x, y.x, s); s = fmaf(x.y, y.y, s);
        s = fmaf(x.z, y.z, s); s = fmaf(x.w, y.w, s);
    }
    s += __shfl_xor(s, 1); s += __shfl_xor(s, 2); s += __shfl_xor(s, 4);
    if (dg == 0) {
        float ls = __expf(lsc[0]);
        out[(size_t)b * 400 + a] = 0.5f * ls * s;
    }
}

// ---------------- bf16x3-split MFMA GEMM -> simT[k=t*8+n][p'] ----------------
// p' = ((by*25+bx)*8 + (b&7))*16 + (a&15)   (tile-local contiguous ordering)
__global__ __launch_bounds__(256)
void gemm_mfma(const u16* __restrict__ Ahi, const u16* __restrict__ Alo,
               const u16* __restrict__ Bhi, const u16* __restrict__ Blo,
               float* __restrict__ C)
{
    __shared__ alignas(16) char smraw[32768];
    u16* s0 = (u16*)smraw;          // Ahi tile 8KB
    u16* s1 = s0 + 4096;            // Alo
    u16* s2 = s0 + 8192;            // Bhi
    u16* s3 = s0 + 12288;           // Blo
    int bid = blockIdx.x;
    int swz = (bid & 7) * 100 + (bid >> 3);     // 800 % 8 == 0: bijective XCD swizzle
    int by = swz / 25, bx = swz % 25;
    int m0 = by * 128, n0 = bx * 128;
    int pblk = (by * 25 + bx) * 128;
    int tid = threadIdx.x, lane = tid & 63, w = tid >> 6;
    int wr = w >> 1, wc = w & 1;
    int srow = tid >> 2, sc = tid & 3;

    f32x4 acc[4][4];
    #pragma unroll
    for (int i = 0; i < 4; ++i)
        #pragma unroll
        for (int jj = 0; jj < 4; ++jj) acc[i][jj] = (f32x4)0.f;

    for (int k0 = 0; k0 < 512; k0 += 32) {
        __syncthreads();
        #pragma unroll
        for (int q = 0; q < 2; ++q) {
            int row = q * 64 + srow;
            int gch = sc ^ ((row >> 2) & 3);   // pre-swizzled global source
            size_t goffA = (size_t)(m0 + row) * 512 + k0 + gch * 8;
            size_t goffB = (size_t)(n0 + row) * 512 + k0 + gch * 8;
            u32 ldso = (u32)(q * 4096 + w * 1024);
            gl_lds16(Ahi + goffA, (char*)s0 + ldso);
            gl_lds16(Alo + goffA, (char*)s1 + ldso);
            gl_lds16(Bhi + goffB, (char*)s2 + ldso);
            gl_lds16(Blo + goffB, (char*)s3 + ldso);
        }
        __syncthreads();
        int lr16 = lane & 15, kg = lane >> 4;
        short8 ah[4], al[4], bh[4], bl[4];
        #pragma unroll
        for (int i = 0; i < 4; ++i) {
            int ar = wr * 64 + i * 16 + lr16;
            u32 offa = (u32)(ar * 64 + (kg ^ ((ar >> 2) & 3)) * 16);
            ah[i] = *(const short8*)((const char*)s0 + offa);
            al[i] = *(const short8*)((const char*)s1 + offa);
            int br = wc * 64 + i * 16 + lr16;
            u32 offb = (u32)(br * 64 + (kg ^ ((br >> 2) & 3)) * 16);
            bh[i] = *(const short8*)((const char*)s2 + offb);
            bl[i] = *(const short8*)((const char*)s3 + offb);
        }
        #pragma unroll
        for (int i = 0; i < 4; ++i)
            #pragma unroll
            for (int jj = 0; jj < 4; ++jj) {
                acc[i][jj] = __builtin_amdgcn_mfma_f32_16x16x32_bf16(ah[i], bh[jj], acc[i][jj], 0, 0, 0);
                acc[i][jj] = __builtin_amdgcn_mfma_f32_16x16x32_bf16(ah[i], bl[jj], acc[i][jj], 0, 0, 0);
                acc[i][jj] = __builtin_amdgcn_mfma_f32_16x16x32_bf16(al[i], bh[jj], acc[i][jj], 0, 0, 0);
            }
    }

    // ---- LDS-transpose epilogue: two passes of [64 k][128 p], XOR-swizzled ----
    float* TB = (float*)smraw;      // 8192 floats = 32KB
    int lr = lane & 15;
    int hi4 = (lane >> 4) * 4;
    int myhalf = lane >> 5;
    int pq = (tid & 31) * 4;
    int kw = tid >> 5;              // 0..7
    __syncthreads();
    #pragma unroll
    for (int h = 0; h < 2; ++h) {
        if (myhalf == h) {
            #pragma unroll
            for (int i = 0; i < 4; ++i)
                #pragma unroll
                for (int jj = 0; jj < 4; ++jj) {
                    int pbase = (wr * 4 + i) * 16 + wc * 8 + jj * 2 + (lr >> 3);
                    int psw = pbase ^ ((lr & 7) << 2);
                    #pragma unroll
                    for (int rr = 0; rr < 4; ++rr) {
                        int kk = ((hi4 & 7) + rr) * 8 + (lr & 7);   // k_local in [0,64)
                        TB[kk * 128 + psw] = acc[i][jj][rr];
                    }
                }
        }
        __syncthreads();
        #pragma unroll
        for (int rep = 0; rep < 8; ++rep) {
            int kl = rep * 8 + kw;
            float4 v = *(const float4*)&TB[kl * 128 + (pq ^ (kw << 2))];
            *(float4*)&C[(size_t)(h * 64 + kl) * BA_ + pblk + pq] = v;
        }
        if (h == 0) __syncthreads();
    }
}

// ---------------- Sinkhorn stage: 1 problem per lane, K in registers (f32x2 packed) ----------------
// simT: [128][BA]; errs: [100][NBLK]; ckc: [6][8][BA]; ckr: [2][16][BA]
__global__ __launch_bounds__(64, 2)
void sink_stage(const float* __restrict__ simT, float* __restrict__ errs,
                float* __restrict__ ckc, float* __restrict__ ckr,
                const int* __restrict__ fnd, int it0, int it1)
{
    if (it0 > 0 && *fnd) return;
    int p = blockIdx.x * 64 + threadIdx.x;
    f32x2 Kv[16][4];
    #pragma unroll
    for (int t = 0; t < 16; ++t)
        #pragma unroll
        for (int n2 = 0; n2 < 4; ++n2) {
            float a0 = simT[(size_t)(t*8 + 2*n2    )*BA_ + p];
            float a1 = simT[(size_t)(t*8 + 2*n2 + 1)*BA_ + p];
            f32x2 kv; kv.x = __expf((a0 - 1.f)*10.f); kv.y = __expf((a1 - 1.f)*10.f);
            Kv[t][n2] = kv;
        }
    f32x2 c2[4];
    float rp[16];
    if (it0 > 0) {
        int slot = it0/16 - 1;
        #pragma unroll
        for (int n2 = 0; n2 < 4; ++n2) {
            f32x2 cv;
            cv.x = ckc[((size_t)(slot*8 + 2*n2    ))*BA_ + p];
            cv.y = ckc[((size_t)(slot*8 + 2*n2 + 1))*BA_ + p];
            c2[n2] = cv;
        }
        int rslot = (it0 == 16) ? 0 : 1;
        #pragma unroll
        for (int t = 0; t < 16; ++t) rp[t] = ckr[((size_t)(rslot*16+t))*BA_ + p];
    } else {
        #pragma unroll
        for (int n2 = 0; n2 < 4; ++n2) c2[n2] = (f32x2)1.f;
        #pragma unroll
        for (int t = 0; t < 16; ++t) rp[t] = 1.f;
    }
    for (int idx = it0; idx < it1; ++idx) {
        f32x2 acc2[4];
        #pragma unroll
        for (int n2 = 0; n2 < 4; ++n2) acc2[n2] = (f32x2)0.f;
        float e = 0.f;
        #pragma unroll
        for (int t = 0; t < 16; ++t) {
            f32x2 s2 = Kv[t][0] * c2[0];
            s2 = PKFMA(Kv[t][1], c2[1], s2);
            s2 = PKFMA(Kv[t][2], c2[2], s2);
            s2 = PKFMA(Kv[t][3], c2[3], s2);
            float r = U_ * RCP(s2.x + s2.y);
            e += fabsf(r - rp[t]);
            rp[t] = r;
            f32x2 rv; rv.x = r; rv.y = r;
            #pragma unroll
            for (int n2 = 0; n2 < 4; ++n2) acc2[n2] = PKFMA(Kv[t][n2], rv, acc2[n2]);
        }
        #pragma unroll
        for (int n2 = 0; n2 < 4; ++n2) {
            f32x2 cv; cv.x = V_ * RCP(acc2[n2].x); cv.y = V_ * RCP(acc2[n2].y);
            c2[n2] = cv;
        }
        e += __shfl_xor(e, 1);  e += __shfl_xor(e, 2);  e += __shfl_xor(e, 4);
        e += __shfl_xor(e, 8);  e += __shfl_xor(e, 16); e += __shfl_xor(e, 32);
        if (threadIdx.x == 0) errs[(size_t)idx * NBLK + blockIdx.x] = e;
        if ((idx & 15) == 15) {
            if (idx < 96) {
                int slot = idx >> 4;
                #pragma unroll
                for (int n2 = 0; n2 < 4; ++n2) {
                    ckc[((size_t)(slot*8 + 2*n2    ))*BA_ + p] = c2[n2].x;
                    ckc[((size_t)(slot*8 + 2*n2 + 1))*BA_ + p] = c2[n2].y;
                }
            }
            if (idx == 15 || idx == 47) {
                int rslot = (idx == 15) ? 0 : 1;
                #pragma unroll
                for (int t = 0; t < 16; ++t) ckr[((size_t)(rslot*16+t))*BA_ + p] = rp[t];
            }
        }
    }
}

// ---------------- fused per-iter reduce + convergence scan (single block) ----------------
__global__ __launch_bounds__(256)
void red_fin_k(const float* __restrict__ errs, int* __restrict__ iters,
               int* __restrict__ fnd, int it0, int it1, int is_final)
{
    if (it0 > 0 && *fnd) return;
    __shared__ float eit[128];
    int nit = it1 - it0;
    int wid = threadIdx.x >> 6, lane = threadIdx.x & 63;
    for (int ii = wid; ii < nit; ii += 4) {
        const float* e = errs + (size_t)(it0 + ii) * NBLK;
        float s = 0.f;
        for (int k = lane; k < NBLK; k += 64) s += e[k];
        s += __shfl_xor(s, 1);  s += __shfl_xor(s, 2);  s += __shfl_xor(s, 4);
        s += __shfl_xor(s, 8);  s += __shfl_xor(s, 16); s += __shfl_xor(s, 32);
        if (lane == 0) eit[ii] = s;
    }
    __syncthreads();
    if (threadIdx.x == 0) {
        for (int ii = 0; ii < nit; ++ii) {
            if (eit[ii] * INV_MEAN < 0.01f) {
                *iters = it0 + ii + 1;
                *fnd = 1;
                return;
            }
        }
        if (is_final) *iters = 100;
    }
}

// ---------------- final pass: replay from checkpoint, score = sum P*sim ----------------
// sim recovered from K: sim = 1 + 0.1*ln(K) = 1 + 0.069314718*log2(K)
__global__ __launch_bounds__(64, 2)
void sink_final(const float* __restrict__ simT, const float* __restrict__ ckc,
                const int* __restrict__ itr, float* __restrict__ score)
{
    int I = *itr;
    int i0 = ((I - 1) >> 4) << 4;
    int p = blockIdx.x * 64 + threadIdx.x;
    f32x2 Kv[16][4];
    #pragma unroll
    for (int t = 0; t < 16; ++t)
        #pragma unroll
        for (int n2 = 0; n2 < 4; ++n2) {
            float a0 = simT[(size_t)(t*8 + 2*n2    )*BA_ + p];
            float a1 = simT[(size_t)(t*8 + 2*n2 + 1)*BA_ + p];
            f32x2 kv; kv.x = __expf((a0 - 1.f)*10.f); kv.y = __expf((a1 - 1.f)*10.f);
            Kv[t][n2] = kv;
        }
    f32x2 c2[4];
    if (i0 > 0) {
        int slot = i0/16 - 1;
        #pragma unroll
        for (int n2 = 0; n2 < 4; ++n2) {
            f32x2 cv;
            cv.x = ckc[((size_t)(slot*8 + 2*n2    ))*BA_ + p];
            cv.y = ckc[((size_t)(slot*8 + 2*n2 + 1))*BA_ + p];
            c2[n2] = cv;
        }
    } else {
        #pragma unroll
        for (int n2 = 0; n2 < 4; ++n2) c2[n2] = (f32x2)1.f;
    }
    float r[16];
    for (int idx = i0; idx < I; ++idx) {
        f32x2 acc2[4];
        #pragma unroll
        for (int n2 = 0; n2 < 4; ++n2) acc2[n2] = (f32x2)0.f;
        #pragma unroll
        for (int t = 0; t < 16; ++t) {
            f32x2 s2 = Kv[t][0] * c2[0];
            s2 = PKFMA(Kv[t][1], c2[1], s2);
            s2 = PKFMA(Kv[t][2], c2[2], s2);
            s2 = PKFMA(Kv[t][3], c2[3], s2);
            r[t] = U_ * RCP(s2.x + s2.y);
            f32x2 rv; rv.x = r[t]; rv.y = r[t];
            #pragma unroll
            for (int n2 = 0; n2 < 4; ++n2) acc2[n2] = PKFMA(Kv[t][n2], rv, acc2[n2]);
        }
        #pragma unroll
        for (int n2 = 0; n2 < 4; ++n2) {
            f32x2 cv; cv.x = V_ * RCP(acc2[n2].x); cv.y = V_ * RCP(acc2[n2].y);
            c2[n2] = cv;
        }
    }
    f32x2 g2 = (f32x2)0.f;
    #pragma unroll
    for (int t = 0; t < 16; ++t) {
        f32x2 rv; rv.x = r[t]; rv.y = r[t];
        #pragma unroll
        for (int n2 = 0; n2 < 4; ++n2) {
            f32x2 sv;
            sv.x = __log2f(Kv[t][n2].x) * 0.069314718f + 1.f;
            sv.y = __log2f(Kv[t][n2].y) * 0.069314718f + 1.f;
            g2 = PKFMA(Kv[t][n2] * c2[n2] * rv, sv, g2);
        }
    }
    score[p] = g2.x + g2.y;
}

// ---------------- final combine (inverts the tile-local p' permutation) ----------------
__global__ __launch_bounds__(256)
void finalize_k(const float* __restrict__ st, const float* __restrict__ ss,
                const float* __restrict__ lsc, float* __restrict__ out)
{
    int i = blockIdx.x * 256 + threadIdx.x;
    int b = i / 400, a = i - b * 400;
    int pp = (((b >> 3) * 25 + (a >> 4)) * 8 + (b & 7)) * 16 + (a & 15);
    float ls = __expf(lsc[0]);
    out[i] += 0.5f * ls * (st[pp] + ss[pp]);
}

extern "C" void kernel_launch(void* const* d_in, const int* in_sizes, int n_in,
                              void* d_out, int out_size, void* d_ws, size_t ws_size,
                              hipStream_t stream)
{
    (void)in_sizes; (void)n_in; (void)out_size; (void)ws_size;
    const float* imf = (const float*)d_in[0];
    const float* ds  = (const float*)d_in[1];   // spatial
    const float* dt  = (const float*)d_in[2];   // temporal
    const float* lsc = (const float*)d_in[3];
    float* out = (float*)d_out;

    float* imf_n    = (float*)d_ws;             // 2,097,152
    float* dsn      = imf_n + 2097152;          // 1,638,400
    float* dtn      = dsn + 1638400;            // 1,638,400
    float* img_pool = dtn + 1638400;            // 131,072
    float* dsum     = img_pool + 131072;        // 204,800
    float* simT     = dsum + 204800;            // 13,107,200
    float* errs     = simT + 13107200;          // 640,000 (use 160,000)
    float* err_iter = errs + 640000;            // 128 (unused, layout kept)
    float* ckc      = err_iter + 128;           // 4,915,200
    float* ckr      = ckc + 4915200;            // 3,276,800
    float* score_t  = ckr + 3276800;            // 102,400
    float* score_s  = score_t + 102400;         // 102,400
    int*   ifound   = (int*)(score_s + 102400); // found[2], iters[2]
    u16*   Ahi      = (u16*)(ifound + 4);       // 2,097,152 u16
    u16*   Alo      = Ahi + 2097152;
    u16*   Bshi     = Alo + 2097152;            // 1,638,400 u16 each
    u16*   Bslo     = Bshi + 1638400;
    u16*   Bthi     = Bslo + 1638400;
    u16*   Btlo     = Bthi + 1638400;
    (void)err_iter;

    norm3_k<<<2624, 256, 0, stream>>>(imf, ds, dt, imf_n, dsn, dtn,
                                      Ahi, Alo, Bshi, Bslo, Bthi, Btlo);
    pools_k<<<1312, 256, 0, stream>>>(imf_n, dsn, dtn, img_pool, dsum, ifound);
    base_k<<<3200, 256, 0, stream>>>(img_pool, dsum, lsc, out);

    for (int set = 0; set < 2; ++set) {
        const u16* Bh = (set == 0) ? Bthi : Bshi;   // temporal first
        const u16* Bl = (set == 0) ? Btlo : Bslo;
        float* score = (set == 0) ? score_t : score_s;
        int* fnd = ifound + set;
        int* itr = ifound + 2 + set;
        gemm_mfma<<<800, 256, 0, stream>>>(Ahi, Alo, Bh, Bl, simT);
        sink_stage<<<NBLK, 64, 0, stream>>>(simT, errs, ckc, ckr, fnd, 0, 16);
        red_fin_k<<<1, 256, 0, stream>>>(errs, itr, fnd, 0, 16, 0);
        sink_stage<<<NBLK, 64, 0, stream>>>(simT, errs, ckc, ckr, fnd, 16, 100);
        red_fin_k<<<1, 256, 0, stream>>>(errs, itr, fnd, 16, 100, 1);
        sink_final<<<NBLK, 64, 0, stream>>>(simT, ckc, itr, score);
    }

    finalize_k<<<400, 256, 0, stream>>>(score_t, score_s, lsc, out);
}